// Round 1
// baseline (65.723 us; speedup 1.0000x reference)
//
#include <hip/hip_runtime.h>
#include <math.h>

#define N_UNITS_C 524288
#define BATCH_C 16384

// ---------------------------------------------------------------------------
// Kernel 1: segment boundary detection on a SORTED segment-id array.
// start[b] = first index i with seg[i] >= b, for b in [0, BATCH]; start[BATCH]=n.
// Each start[b] is written by exactly one thread -> deterministic, no init needed.
// ---------------------------------------------------------------------------
__global__ __launch_bounds__(256) void seg_starts_kernel(
    const int* __restrict__ seg, int n, int* __restrict__ start)
{
    int i = blockIdx.x * blockDim.x + threadIdx.x;
    if (i >= n) return;
    int s = seg[i];
    int prev = (i == 0) ? -1 : seg[i - 1];
    for (int b = prev + 1; b <= s; ++b) start[b] = i;
    if (i == n - 1) {
        for (int b = s + 1; b <= BATCH_C; ++b) start[b] = n;
    }
}

// ---------------------------------------------------------------------------
// Kernel 2: fused per-unit MLP (9 -> 64, ReLU) + ragged segment sum.
// One wave (64 lanes) per segment; lane j owns column j of W1 (9 regs) and
// b1[j]. Iterates the segment's contiguous units with wave-uniform feature
// reads (scalar-load friendly). Writes pooled[seg][side*64 + j] exactly once.
// ---------------------------------------------------------------------------
__global__ __launch_bounds__(256) void pool_kernel(
    const float* __restrict__ lfeats, const float* __restrict__ rfeats,
    const int* __restrict__ lstart, const int* __restrict__ rstart,
    const float* __restrict__ W1, const float* __restrict__ b1,
    float* __restrict__ pooled)
{
    const int lane = threadIdx.x & 63;
    const int wave = threadIdx.x >> 6;
    const int side = blockIdx.y;

    int segidx = blockIdx.x * 4 + wave;
    segidx = __builtin_amdgcn_readfirstlane(segidx);

    const float* __restrict__ feats = side ? rfeats : lfeats;
    const int* __restrict__ start = side ? rstart : lstart;

    // lane j holds W1[:, j] (column) in registers
    float w[9];
#pragma unroll
    for (int k = 0; k < 9; ++k) w[k] = W1[k * 64 + lane];
    const float bias = b1[lane];

    const int s = start[segidx];
    const int e = start[segidx + 1];

    float acc = 0.0f;
    for (int i = s; i < e; ++i) {
        const float* __restrict__ f = feats + (size_t)i * 9;
        float h = bias;
#pragma unroll
        for (int k = 0; k < 9; ++k) h = fmaf(f[k], w[k], h);
        acc += fmaxf(h, 0.0f);
    }

    pooled[(size_t)segidx * 128 + side * 64 + lane] = acc;
}

// ---------------------------------------------------------------------------
// Kernel 3: head MLP. combined[B,128] @ Wc1[128,32] + bc1 -> relu
//           -> @ Wc2[32,1] + bc2 -> sigmoid.
// 2 rows per wave: lanes [0..31] = row A hidden units, [32..63] = row B.
// Wc1 staged in LDS; 32-lane shfl-xor reduce for the final dot.
// ---------------------------------------------------------------------------
__global__ __launch_bounds__(256) void head_kernel(
    const float* __restrict__ pooled, const float* __restrict__ Wc1,
    const float* __restrict__ bc1, const float* __restrict__ Wc2,
    const float* __restrict__ bc2, float* __restrict__ out)
{
    __shared__ float sW[128 * 32];
    __shared__ float sb[32];
    __shared__ float sw2[32];

    for (int t = threadIdx.x; t < 128 * 32; t += 256) sW[t] = Wc1[t];
    if (threadIdx.x < 32) {
        sb[threadIdx.x] = bc1[threadIdx.x];
        sw2[threadIdx.x] = Wc2[threadIdx.x];
    }
    __syncthreads();

    const int lane = threadIdx.x & 63;
    const int wave = threadIdx.x >> 6;
    const int half = lane >> 5;   // which of the 2 rows this half-wave owns
    const int j = lane & 31;      // hidden unit index

    const int row = blockIdx.x * 8 + wave * 2 + half;
    const float* __restrict__ p = pooled + (size_t)row * 128;

    float acc = sb[j];
#pragma unroll 16
    for (int k = 0; k < 128; ++k) acc = fmaf(p[k], sW[k * 32 + j], acc);

    float h = fmaxf(acc, 0.0f) * sw2[j];
    // reduce over j within each 32-lane half (masks 16..1 never cross bit 5)
#pragma unroll
    for (int off = 16; off > 0; off >>= 1) h += __shfl_xor(h, off, 64);

    if (j == 0) {
        float logit = h + bc2[0];
        out[row] = 1.0f / (1.0f + expf(-logit));
    }
}

// ---------------------------------------------------------------------------
extern "C" void kernel_launch(void* const* d_in, const int* in_sizes, int n_in,
                              void* d_out, int out_size, void* d_ws, size_t ws_size,
                              hipStream_t stream)
{
    const float* lfeats = (const float*)d_in[0];
    const float* rfeats = (const float*)d_in[1];
    const int*   lseg   = (const int*)d_in[2];
    const int*   rseg   = (const int*)d_in[3];
    const float* W1     = (const float*)d_in[4];
    const float* b1     = (const float*)d_in[5];
    const float* Wc1    = (const float*)d_in[6];
    const float* bc1    = (const float*)d_in[7];
    const float* Wc2    = (const float*)d_in[8];
    const float* bc2    = (const float*)d_in[9];
    float* out = (float*)d_out;

    const int n = in_sizes[2];  // N_UNITS per side

    // workspace layout: pooled [BATCH][128] f32, then two start arrays [BATCH+1]
    float* pooled = (float*)d_ws;
    int* lstart = (int*)((char*)d_ws + (size_t)BATCH_C * 128 * sizeof(float));
    int* rstart = lstart + (BATCH_C + 16);

    seg_starts_kernel<<<(n + 255) / 256, 256, 0, stream>>>(lseg, n, lstart);
    seg_starts_kernel<<<(n + 255) / 256, 256, 0, stream>>>(rseg, n, rstart);

    pool_kernel<<<dim3(BATCH_C / 4, 2), 256, 0, stream>>>(
        lfeats, rfeats, lstart, rstart, W1, b1, pooled);

    head_kernel<<<BATCH_C / 8, 256, 0, stream>>>(pooled, Wc1, bc1, Wc2, bc2, out);
}

// Round 2
// 54.673 us; speedup vs baseline: 1.2021x; 1.2021x over previous
//
#include <hip/hip_runtime.h>
#include <math.h>

#define N_UNITS_C 524288
#define BATCH_C 16384

typedef float f32x4 __attribute__((ext_vector_type(4)));
typedef f32x4 __attribute__((aligned(4))) f32x4_u;   // 4-byte-aligned vector load

// ---------------------------------------------------------------------------
// Kernel 1: segment boundary detection on a SORTED segment-id array.
// start[b] = first index i with seg[i] >= b; start[BATCH]=n. Each element
// written exactly once -> deterministic, no init needed.
// ---------------------------------------------------------------------------
__global__ __launch_bounds__(256) void seg_starts_kernel(
    const int* __restrict__ seg, int n, int* __restrict__ start)
{
    int i = blockIdx.x * blockDim.x + threadIdx.x;
    if (i >= n) return;
    int s = seg[i];
    int prev = (i == 0) ? -1 : seg[i - 1];
    for (int b = prev + 1; b <= s; ++b) start[b] = i;
    if (i == n - 1) {
        for (int b = s + 1; b <= BATCH_C; ++b) start[b] = n;
    }
}

// ---------------------------------------------------------------------------
// Kernel 2: fused per-unit MLP (9 -> 64, ReLU) + ragged segment sum.
// One wave per segment. Per 64-unit chunk:
//   stage: lane u loads unit (base+u)'s 9 floats (dwordx4,dwordx4,dword) and
//          ds_writes them to a 48B-padded slot (slot stride 12 dwords ->
//          group reads are bank-conflict-free).
//   compute: 8 groups x 8 lanes; group g handles unit p*8+g of pass p; each
//          lane reads that unit's 9 feats from LDS (group-uniform broadcast)
//          and FMAs its 8 channels (W1 columns j+8t held in 72 VGPRs).
// End: 3x shfl_xor (8,16,32) reduce across groups; lane stores channel==lane.
// ---------------------------------------------------------------------------
__global__ __launch_bounds__(256, 4) void pool_kernel(
    const float* __restrict__ lfeats, const float* __restrict__ rfeats,
    const int* __restrict__ lstart, const int* __restrict__ rstart,
    const float* __restrict__ W1, const float* __restrict__ b1,
    float* __restrict__ pooled, int nunits)
{
    const int tid  = threadIdx.x;
    const int lane = tid & 63;
    const int wv   = tid >> 6;
    const int j    = lane & 7;   // channel sub-index
    const int g    = lane >> 3;  // group (unit-within-pass)
    const int side = blockIdx.y;
    const int seg  = blockIdx.x * 4 + wv;

    __shared__ float lds[4][64 * 12];   // 48 B slot per unit, 64 units per wave
    float* __restrict__ slb = lds[wv];

    const float* __restrict__ feats = side ? rfeats : lfeats;
    const int*   __restrict__ start = side ? rstart : lstart;

    // per-lane weights: w[k][t] = W1[k][j + 8t]; bias[t] = b1[j + 8t]
    float w[9][8];
    float bias[8];
#pragma unroll
    for (int t = 0; t < 8; ++t) {
        bias[t] = b1[j + 8 * t];
#pragma unroll
        for (int k = 0; k < 9; ++k) w[k][t] = W1[k * 64 + j + 8 * t];
    }

    const int s = start[seg];
    const int e = start[seg + 1];

    float acc[8] = {0.f, 0.f, 0.f, 0.f, 0.f, 0.f, 0.f, 0.f};

    for (int base = s; base < e; base += 64) {
        // ---- stage 64 units into LDS (lane u -> unit base+u) ----
        int um = base + lane;
        if (um > nunits - 1) um = nunits - 1;   // clamp: garbage slots are masked out
        const float* __restrict__ fp = feats + (size_t)um * 9;
        f32x4 a0 = *reinterpret_cast<const f32x4_u*>(fp);
        f32x4 a1 = *reinterpret_cast<const f32x4_u*>(fp + 4);
        float a2 = fp[8];
        float* sp = slb + lane * 12;
        *reinterpret_cast<f32x4*>(sp)     = a0;   // 16B-aligned ds_write_b128
        *reinterpret_cast<f32x4*>(sp + 4) = a1;
        sp[8] = a2;
        // same-wave LDS RAW: DS pipe is in-order per wave; fence the compiler
        // and drain the write count before cross-lane reads.
        asm volatile("s_waitcnt lgkmcnt(0)" ::: "memory");

        const int rem   = e - base;
        const int cnt   = rem < 64 ? rem : 64;  // units in this chunk
        const int nfull = cnt >> 3;             // unmasked passes
        const float* __restrict__ gb = slb + g * 12;

        for (int p = 0; p < nfull; ++p) {
            const float* __restrict__ fb = gb + p * 96;  // (p*8+g)*12
            f32x4 A = *reinterpret_cast<const f32x4*>(fb);
            f32x4 B = *reinterpret_cast<const f32x4*>(fb + 4);
            float C = fb[8];
#pragma unroll
            for (int t = 0; t < 8; ++t) {
                float h = bias[t];
                h = fmaf(A.x, w[0][t], h);
                h = fmaf(A.y, w[1][t], h);
                h = fmaf(A.z, w[2][t], h);
                h = fmaf(A.w, w[3][t], h);
                h = fmaf(B.x, w[4][t], h);
                h = fmaf(B.y, w[5][t], h);
                h = fmaf(B.z, w[6][t], h);
                h = fmaf(B.w, w[7][t], h);
                h = fmaf(C,   w[8][t], h);
                acc[t] += fmaxf(h, 0.f);
            }
        }
        if (cnt & 7) {  // masked tail pass
            const float* __restrict__ fb = gb + nfull * 96;
            const bool valid = g < (cnt & 7);
            f32x4 A = *reinterpret_cast<const f32x4*>(fb);
            f32x4 B = *reinterpret_cast<const f32x4*>(fb + 4);
            float C = fb[8];
#pragma unroll
            for (int t = 0; t < 8; ++t) {
                float h = bias[t];
                h = fmaf(A.x, w[0][t], h);
                h = fmaf(A.y, w[1][t], h);
                h = fmaf(A.z, w[2][t], h);
                h = fmaf(A.w, w[3][t], h);
                h = fmaf(B.x, w[4][t], h);
                h = fmaf(B.y, w[5][t], h);
                h = fmaf(B.z, w[6][t], h);
                h = fmaf(B.w, w[7][t], h);
                h = fmaf(C,   w[8][t], h);
                acc[t] += valid ? fmaxf(h, 0.f) : 0.f;
            }
        }
    }

    // ---- reduce across groups (lane bits 3..5) ----
#pragma unroll
    for (int t = 0; t < 8; ++t) {
        acc[t] += __shfl_xor(acc[t], 8, 64);
        acc[t] += __shfl_xor(acc[t], 16, 64);
        acc[t] += __shfl_xor(acc[t], 32, 64);
    }
    // lane writes channel c == lane == j + 8g  ->  acc[t = g]
    float outv = acc[0];
#pragma unroll
    for (int t = 1; t < 8; ++t) if (g == t) outv = acc[t];

    pooled[(size_t)seg * 128 + side * 64 + lane] = outv;
}

// ---------------------------------------------------------------------------
// Kernel 3: head MLP. combined[B,128] @ Wc1[128,32] + bc1 -> relu
//           -> @ Wc2[32,1] + bc2 -> sigmoid.
// ---------------------------------------------------------------------------
__global__ __launch_bounds__(256) void head_kernel(
    const float* __restrict__ pooled, const float* __restrict__ Wc1,
    const float* __restrict__ bc1, const float* __restrict__ Wc2,
    const float* __restrict__ bc2, float* __restrict__ out)
{
    __shared__ float sW[128 * 32];
    __shared__ float sb[32];
    __shared__ float sw2[32];

    for (int t = threadIdx.x; t < 128 * 32; t += 256) sW[t] = Wc1[t];
    if (threadIdx.x < 32) {
        sb[threadIdx.x] = bc1[threadIdx.x];
        sw2[threadIdx.x] = Wc2[threadIdx.x];
    }
    __syncthreads();

    const int lane = threadIdx.x & 63;
    const int wave = threadIdx.x >> 6;
    const int half = lane >> 5;
    const int j = lane & 31;

    const int row = blockIdx.x * 8 + wave * 2 + half;
    const float* __restrict__ p = pooled + (size_t)row * 128;

    float acc = sb[j];
#pragma unroll 16
    for (int k = 0; k < 128; ++k) acc = fmaf(p[k], sW[k * 32 + j], acc);

    float h = fmaxf(acc, 0.0f) * sw2[j];
#pragma unroll
    for (int off = 16; off > 0; off >>= 1) h += __shfl_xor(h, off, 64);

    if (j == 0) {
        float logit = h + bc2[0];
        out[row] = 1.0f / (1.0f + expf(-logit));
    }
}

// ---------------------------------------------------------------------------
extern "C" void kernel_launch(void* const* d_in, const int* in_sizes, int n_in,
                              void* d_out, int out_size, void* d_ws, size_t ws_size,
                              hipStream_t stream)
{
    const float* lfeats = (const float*)d_in[0];
    const float* rfeats = (const float*)d_in[1];
    const int*   lseg   = (const int*)d_in[2];
    const int*   rseg   = (const int*)d_in[3];
    const float* W1     = (const float*)d_in[4];
    const float* b1     = (const float*)d_in[5];
    const float* Wc1    = (const float*)d_in[6];
    const float* bc1    = (const float*)d_in[7];
    const float* Wc2    = (const float*)d_in[8];
    const float* bc2    = (const float*)d_in[9];
    float* out = (float*)d_out;

    const int n = in_sizes[2];  // N_UNITS per side

    float* pooled = (float*)d_ws;
    int* lstart = (int*)((char*)d_ws + (size_t)BATCH_C * 128 * sizeof(float));
    int* rstart = lstart + (BATCH_C + 16);

    seg_starts_kernel<<<(n + 255) / 256, 256, 0, stream>>>(lseg, n, lstart);
    seg_starts_kernel<<<(n + 255) / 256, 256, 0, stream>>>(rseg, n, rstart);

    pool_kernel<<<dim3(BATCH_C / 4, 2), 256, 0, stream>>>(
        lfeats, rfeats, lstart, rstart, W1, b1, pooled, n);

    head_kernel<<<BATCH_C / 8, 256, 0, stream>>>(pooled, Wc1, bc1, Wc2, bc2, out);
}

// Round 3
// 50.008 us; speedup vs baseline: 1.3142x; 1.0933x over previous
//
#include <hip/hip_runtime.h>
#include <math.h>

#define N_UNITS_C 524288
#define BATCH_C 16384
#define SEGS_PER_WAVE 8

typedef float f32x4 __attribute__((ext_vector_type(4)));
typedef f32x4 __attribute__((aligned(4))) f32x4_u;   // 4-byte-aligned vector load

struct F9 { f32x4 a; f32x4 b; float c; };
__device__ inline F9 load9(const float* __restrict__ p) {
    F9 r;
    r.a = *reinterpret_cast<const f32x4_u*>(p);
    r.b = *reinterpret_cast<const f32x4_u*>(p + 4);
    r.c = p[8];
    return r;
}

// ---------------------------------------------------------------------------
// Kernel 1: segment boundary detection for BOTH sides (grid.y = side).
// start[b] = first index i with seg[i] >= b; start[BATCH]=n.
// ---------------------------------------------------------------------------
__global__ __launch_bounds__(256) void seg_starts_kernel(
    const int* __restrict__ lseg, const int* __restrict__ rseg, int n,
    int* __restrict__ lstart, int* __restrict__ rstart)
{
    const int* __restrict__ seg = blockIdx.y ? rseg : lseg;
    int* __restrict__ start = blockIdx.y ? rstart : lstart;
    int i = blockIdx.x * blockDim.x + threadIdx.x;
    if (i >= n) return;
    int s = seg[i];
    int prev = (i == 0) ? -1 : seg[i - 1];
    for (int b = prev + 1; b <= s; ++b) start[b] = i;
    if (i == n - 1) {
        for (int b = s + 1; b <= BATCH_C; ++b) start[b] = n;
    }
}

// ---------------------------------------------------------------------------
// Kernel 2: fused per-unit MLP (9 -> 64, ReLU) + ragged segment sum.
// Lane = channel (64 ch). Each lane holds W1 column entries for its channel
// (10 regs total). One wave handles 8 consecutive segments = ~256 units,
// streamed through double-buffered 64-unit LDS windows (reg-prefetched).
// Per unit: 3 wave-uniform ds_reads (broadcast) + 9 FMA + relu + add.
// Accumulator is the per-channel segment sum -> flush = single store.
// Every segment written exactly once -> deterministic.
// ---------------------------------------------------------------------------
__global__ __launch_bounds__(256, 4) void pool_kernel(
    const float* __restrict__ lfeats, const float* __restrict__ rfeats,
    const int* __restrict__ lstart, const int* __restrict__ rstart,
    const float* __restrict__ W1, const float* __restrict__ b1,
    float* __restrict__ pooled, int nunits)
{
    const int lane = threadIdx.x & 63;
    const int wv   = threadIdx.x >> 6;
    const int side = blockIdx.y;
    const int S0   = (blockIdx.x * 4 + wv) * SEGS_PER_WAVE;

    __shared__ float lds[4][2][64 * 12];   // 48B slot/unit, dbuf, per-wave

    const float* __restrict__ feats = side ? rfeats : lfeats;
    const int*   __restrict__ start = side ? rstart : lstart;

    // lane owns channel `lane`: W1[:, lane] + b1[lane]  (10 regs)
    float w0 = W1[0 * 64 + lane], w1 = W1[1 * 64 + lane], w2 = W1[2 * 64 + lane];
    float w3 = W1[3 * 64 + lane], w4 = W1[4 * 64 + lane], w5 = W1[5 * 64 + lane];
    float w6 = W1[6 * 64 + lane], w7 = W1[7 * 64 + lane], w8 = W1[8 * 64 + lane];
    const float bias = b1[lane];

    // lane l (l<=8) loads start[S0+l]; broadcast via shfl
    int sv = start[S0 + (lane < 9 ? lane : 8)];
    const int s_abs   = __shfl(sv, 0, 64);
    const int end_abs = __shfl(sv, 8, 64);

    int c = 0;                         // local segment cursor 0..7
    int e_c = __shfl(sv, 1, 64);       // absolute end of segment c

    float acc = 0.0f;
    float* __restrict__ sl = &lds[wv][0][0];
    int bufsel = 0;

    int base = s_abs;
    F9 pre;
    if (base < end_abs)
        pre = load9(feats + (size_t)(base + lane < nunits ? base + lane : nunits - 1) * 9);

    while (base < end_abs) {
        float* __restrict__ bp = sl + bufsel * 768;
        float* sp = bp + lane * 12;
        *reinterpret_cast<f32x4*>(sp)     = pre.a;   // ds_write_b128
        *reinterpret_cast<f32x4*>(sp + 4) = pre.b;
        sp[8] = pre.c;

        int nbase = base + 64;
        if (nbase < end_abs)  // prefetch next window while computing this one
            pre = load9(feats + (size_t)(nbase + lane < nunits ? nbase + lane : nunits - 1) * 9);

        // drain ds_writes before cross-lane reads (in-order DS pipe, same wave)
        asm volatile("s_waitcnt lgkmcnt(0)" ::: "memory");

        int wend = end_abs - base; if (wend > 64) wend = 64;
        int ul = 0;
        while (c < SEGS_PER_WAVE) {
            int ecl = e_c - base;                 // may exceed wend
            int hi = ecl < wend ? ecl : wend;
            for (int i = ul; i < hi; ++i) {
                const float* __restrict__ fb = bp + i * 12;   // wave-uniform addr
                f32x4 A  = *reinterpret_cast<const f32x4*>(fb);
                f32x4 Bv = *reinterpret_cast<const f32x4*>(fb + 4);
                float Cv = fb[8];
                float h = bias;
                h = fmaf(A.x,  w0, h);
                h = fmaf(A.y,  w1, h);
                h = fmaf(A.z,  w2, h);
                h = fmaf(A.w,  w3, h);
                h = fmaf(Bv.x, w4, h);
                h = fmaf(Bv.y, w5, h);
                h = fmaf(Bv.z, w6, h);
                h = fmaf(Bv.w, w7, h);
                h = fmaf(Cv,   w8, h);
                acc += fmaxf(h, 0.0f);
            }
            ul = hi;
            if (ecl <= wend) {   // segment c complete (possibly empty) -> flush
                pooled[(size_t)(S0 + c) * 128 + side * 64 + lane] = acc;
                acc = 0.0f;
                ++c;
                int idx = c < SEGS_PER_WAVE ? c + 1 : SEGS_PER_WAVE;
                e_c = __shfl(sv, idx, 64);
            } else break;        // segment continues into next window
        }
        base = nbase;
        bufsel ^= 1;
    }
    // trailing (all-empty waves / empty tail segments): acc == 0 here
    while (c < SEGS_PER_WAVE) {
        pooled[(size_t)(S0 + c) * 128 + side * 64 + lane] = 0.0f;
        ++c;
    }
}

// ---------------------------------------------------------------------------
// Kernel 3: head MLP. combined[B,128] @ Wc1[128,32] + bc1 -> relu
//           -> @ Wc2[32,1] + bc2 -> sigmoid.
// ---------------------------------------------------------------------------
__global__ __launch_bounds__(256) void head_kernel(
    const float* __restrict__ pooled, const float* __restrict__ Wc1,
    const float* __restrict__ bc1, const float* __restrict__ Wc2,
    const float* __restrict__ bc2, float* __restrict__ out)
{
    __shared__ float sW[128 * 32];
    __shared__ float sb[32];
    __shared__ float sw2[32];

    for (int t = threadIdx.x; t < 128 * 32; t += 256) sW[t] = Wc1[t];
    if (threadIdx.x < 32) {
        sb[threadIdx.x] = bc1[threadIdx.x];
        sw2[threadIdx.x] = Wc2[threadIdx.x];
    }
    __syncthreads();

    const int lane = threadIdx.x & 63;
    const int wave = threadIdx.x >> 6;
    const int half = lane >> 5;
    const int j = lane & 31;

    const int row = blockIdx.x * 8 + wave * 2 + half;
    const float* __restrict__ p = pooled + (size_t)row * 128;

    float acc = sb[j];
#pragma unroll 16
    for (int k = 0; k < 128; ++k) acc = fmaf(p[k], sW[k * 32 + j], acc);

    float h = fmaxf(acc, 0.0f) * sw2[j];
#pragma unroll
    for (int off = 16; off > 0; off >>= 1) h += __shfl_xor(h, off, 64);

    if (j == 0) {
        float logit = h + bc2[0];
        out[row] = 1.0f / (1.0f + expf(-logit));
    }
}

// ---------------------------------------------------------------------------
extern "C" void kernel_launch(void* const* d_in, const int* in_sizes, int n_in,
                              void* d_out, int out_size, void* d_ws, size_t ws_size,
                              hipStream_t stream)
{
    const float* lfeats = (const float*)d_in[0];
    const float* rfeats = (const float*)d_in[1];
    const int*   lseg   = (const int*)d_in[2];
    const int*   rseg   = (const int*)d_in[3];
    const float* W1     = (const float*)d_in[4];
    const float* b1     = (const float*)d_in[5];
    const float* Wc1    = (const float*)d_in[6];
    const float* bc1    = (const float*)d_in[7];
    const float* Wc2    = (const float*)d_in[8];
    const float* bc2    = (const float*)d_in[9];
    float* out = (float*)d_out;

    const int n = in_sizes[2];  // N_UNITS per side

    float* pooled = (float*)d_ws;
    int* lstart = (int*)((char*)d_ws + (size_t)BATCH_C * 128 * sizeof(float));
    int* rstart = lstart + (BATCH_C + 16);

    seg_starts_kernel<<<dim3((n + 255) / 256, 2), 256, 0, stream>>>(
        lseg, rseg, n, lstart, rstart);

    pool_kernel<<<dim3(BATCH_C / (SEGS_PER_WAVE * 4), 2), 256, 0, stream>>>(
        lfeats, rfeats, lstart, rstart, W1, b1, pooled, n);

    head_kernel<<<BATCH_C / 8, 256, 0, stream>>>(pooled, Wc1, bc1, Wc2, bc2, out);
}